// Round 1
// baseline (263.031 us; speedup 1.0000x reference)
//
#include <hip/hip_runtime.h>
#include <stdint.h>

// NeiAttention: B=512, N=32, S=16, EF=64, NF=D=128, K=192
// Fully fused: projection (bf16 MFMA) + softmax attention, v stays in LDS.

typedef __attribute__((ext_vector_type(8))) short short8;
typedef __attribute__((ext_vector_type(4))) float float4_t;
typedef __attribute__((ext_vector_type(4))) unsigned short ushort4_t;

#define GRID_ 1024
#define ITERS_ 16   // 1024 * 16 = 16384 = B*N

__device__ __forceinline__ unsigned short f2bf(float f) {
    uint32_t u = __float_as_uint(f);
    u += 0x7fffu + ((u >> 16) & 1u);   // RNE
    return (unsigned short)(u >> 16);
}

// A-fragment-packed LDS offset (ushort units) for element (s, k):
// kstep q = k/32, quad = (k%32)/8, j = k%8; owner lane = quad*16 + s.
__device__ __forceinline__ int aoff(int s, int kc) {
    return (((kc >> 5) * 64) + (((kc & 31) >> 3) * 16) + s) * 8 + (kc & 7);
}

__global__ __launch_bounds__(256) void nei_attn_kernel(
    const float* __restrict__ x,
    const float* __restrict__ rel,
    const float* __restrict__ node,
    const float* __restrict__ W,
    const float* __restrict__ bias,
    float* __restrict__ out)
{
    __shared__ __align__(16) unsigned short lds_a[6 * 64 * 8]; // 6 KB bf16 A-frags
    __shared__ float lds_x[128];
    __shared__ float lds_v[16 * 132];                          // stride 132: 2-way only
    __shared__ float lds_ap[256];
    __shared__ float lds_alpha[16];

    const int t    = threadIdx.x;
    const int lane = t & 63;
    const int wv   = t >> 6;        // wave 0..3
    const int l15  = lane & 15;
    const int quad = lane >> 4;

    // ---- W^T B-fragments + bias: loaded ONCE, live in registers ----
    // wave wv owns output-column tiles c0 = 2*wv, c1 = 2*wv+1.
    short8 bf0[6], bf1[6];
    const int row0 = wv * 32 + l15;     // output dim d for tile 0
    const int row1 = row0 + 16;         // tile 1
    const float bias0 = bias[row0];
    const float bias1 = bias[row1];
    #pragma unroll
    for (int q = 0; q < 6; ++q) {
        const float* p0 = W + row0 * 192 + q * 32 + quad * 8;
        const float* p1 = W + row1 * 192 + q * 32 + quad * 8;
        float4_t a0 = *(const float4_t*)p0;
        float4_t a1 = *(const float4_t*)(p0 + 4);
        float4_t c0 = *(const float4_t*)p1;
        float4_t c1 = *(const float4_t*)(p1 + 4);
        short8 f0, f1;
        f0[0] = (short)f2bf(a0.x); f0[1] = (short)f2bf(a0.y);
        f0[2] = (short)f2bf(a0.z); f0[3] = (short)f2bf(a0.w);
        f0[4] = (short)f2bf(a1.x); f0[5] = (short)f2bf(a1.y);
        f0[6] = (short)f2bf(a1.z); f0[7] = (short)f2bf(a1.w);
        f1[0] = (short)f2bf(c0.x); f1[1] = (short)f2bf(c0.y);
        f1[2] = (short)f2bf(c0.z); f1[3] = (short)f2bf(c0.w);
        f1[4] = (short)f2bf(c1.x); f1[5] = (short)f2bf(c1.y);
        f1[6] = (short)f2bf(c1.z); f1[7] = (short)f2bf(c1.w);
        bf0[q] = f0; bf1[q] = f1;
    }

    // Staging map: 768 float4s per (b,n) tile; thread t handles 3:
    //   c=0: rel   f4 #t      -> (s = t>>4,      k = (t&15)*4)
    //   c=1: node  f4 #t      -> (s = t>>5,      k = 64 + (t&31)*4)
    //   c=2: node  f4 #(t+256)-> (s = 8+(t>>5),  k = 64 + (t&31)*4)
    const int s0 = t >> 4,       kc0 = (t & 15) << 2;
    const int s1 = t >> 5,       kc1 = 64 + ((t & 31) << 2);
    const int s2 = s1 + 8;
    const int ao0 = aoff(s0, kc0);
    const int ao1 = aoff(s1, kc1);
    const int ao2 = aoff(s2, kc1);

    int idx = blockIdx.x * ITERS_;

    // ---- prefetch iteration 0 ----
    float4_t pf0, pf1, pf2, pfx;
    {
        const float* pr = rel  + idx * 1024;   // 16*64 floats per (b,n)
        const float* pn = node + idx * 2048;   // 16*128 floats per (b,n)
        pf0 = *(const float4_t*)(pr + t * 4);
        pf1 = *(const float4_t*)(pn + t * 4);
        pf2 = *(const float4_t*)(pn + 1024 + t * 4);
        if (t < 32) pfx = *(const float4_t*)(x + idx * 128 + t * 4);
    }

    for (int it = 0; it < ITERS_; ++it) {
        // ---- stage regs -> LDS (bf16, A-fragment packed) ----
        {
            ushort4_t u;
            u[0] = f2bf(pf0.x); u[1] = f2bf(pf0.y); u[2] = f2bf(pf0.z); u[3] = f2bf(pf0.w);
            *(ushort4_t*)&lds_a[ao0] = u;
            u[0] = f2bf(pf1.x); u[1] = f2bf(pf1.y); u[2] = f2bf(pf1.z); u[3] = f2bf(pf1.w);
            *(ushort4_t*)&lds_a[ao1] = u;
            u[0] = f2bf(pf2.x); u[1] = f2bf(pf2.y); u[2] = f2bf(pf2.z); u[3] = f2bf(pf2.w);
            *(ushort4_t*)&lds_a[ao2] = u;
            if (t < 32) *(float4_t*)&lds_x[t * 4] = pfx;
        }
        __syncthreads();   // (1) lds_a / lds_x ready

        // ---- prefetch next iteration (latency hidden under MFMA+attention) ----
        if (it + 1 < ITERS_) {
            const int nidx = idx + 1;
            const float* pr = rel  + nidx * 1024;
            const float* pn = node + nidx * 2048;
            pf0 = *(const float4_t*)(pr + t * 4);
            pf1 = *(const float4_t*)(pn + t * 4);
            pf2 = *(const float4_t*)(pn + 1024 + t * 4);
            if (t < 32) pfx = *(const float4_t*)(x + nidx * 128 + t * 4);
        }

        // ---- projection: v(16x128) = feat(16x192) @ W^T, 2 tiles/wave ----
        float4_t acc0 = {0.f, 0.f, 0.f, 0.f};
        float4_t acc1 = {0.f, 0.f, 0.f, 0.f};
        #pragma unroll
        for (int q = 0; q < 6; ++q) {
            short8 af = *(const short8*)&lds_a[(q * 64 + lane) * 8];
            acc0 = __builtin_amdgcn_mfma_f32_16x16x32_bf16(af, bf0[q], acc0, 0, 0, 0);
            acc1 = __builtin_amdgcn_mfma_f32_16x16x32_bf16(af, bf1[q], acc1, 0, 0, 0);
        }

        // C/D layout: lane holds D[quad*4+r][l15]; col tile base = wv*32 (+16)
        const int col0 = wv * 32 + l15;
        const int rb = quad * 4;
        #pragma unroll
        for (int r = 0; r < 4; ++r) {
            lds_v[(rb + r) * 132 + col0]      = acc0[r] + bias0;
            lds_v[(rb + r) * 132 + col0 + 16] = acc1[r] + bias1;
        }
        __syncthreads();   // (2) lds_v ready

        // ---- alpha partials: thread (s = t>>4, d0 = t&15) sums 8 strided d ----
        {
            const int sA = t >> 4, dA = t & 15;
            float p = 0.f;
            #pragma unroll
            for (int j = 0; j < 8; ++j) {
                const int d = dA + (j << 4);
                p += lds_x[d] * lds_v[sA * 132 + d];
            }
            lds_ap[t] = p;
        }
        __syncthreads();   // (3)

        if (t < 16) {
            float a = 0.f;
            #pragma unroll
            for (int j = 0; j < 16; ++j) a += lds_ap[t * 16 + j];
            lds_alpha[t] = a * 0.08838834764831845f;   // 1/sqrt(128)
        }
        __syncthreads();   // (4)

        // ---- softmax + weighted sum; threads 0..127 each own one d ----
        if (t < 128) {
            float m = lds_alpha[0];
            #pragma unroll
            for (int s = 1; s < 16; ++s) m = fmaxf(m, lds_alpha[s]);
            float e[16], den = 0.f;
            #pragma unroll
            for (int s = 0; s < 16; ++s) { e[s] = __expf(lds_alpha[s] - m); den += e[s]; }
            float o = 0.f;
            #pragma unroll
            for (int s = 0; s < 16; ++s) o += e[s] * lds_v[s * 132 + t];
            out[idx * 128 + t] = o / den;
        }
        ++idx;
        // no trailing barrier needed: next-iter writes touch lds_a/lds_x only,
        // whose readers all retired before barriers (2)/(3) of this iteration.
    }
}

extern "C" void kernel_launch(void* const* d_in, const int* in_sizes, int n_in,
                              void* d_out, int out_size, void* d_ws, size_t ws_size,
                              hipStream_t stream) {
    const float* x    = (const float*)d_in[0];
    const float* rel  = (const float*)d_in[1];
    const float* node = (const float*)d_in[2];
    const float* W    = (const float*)d_in[3];
    const float* bias = (const float*)d_in[4];
    float* out = (float*)d_out;
    hipLaunchKernelGGL(nei_attn_kernel, dim3(GRID_), dim3(256), 0, stream,
                       x, rel, node, W, bias, out);
}